// Round 1
// baseline (278.063 us; speedup 1.0000x reference)
//
#include <hip/hip_runtime.h>

// B=8, N=2048, D_IN=D_OUT=512. out fp32 [8,2048,512].
// ws layout (bytes): xb@0 (16M), Qb@16M, Kb@32M, Vb@48M, Vt@64M, Wt@80M(+1.5M) -> ~81.5MB needed.

typedef __bf16 bf16x8 __attribute__((ext_vector_type(8)));
typedef float f32x4 __attribute__((ext_vector_type(4)));

#define AS1G __attribute__((address_space(1)))
#define AS3L __attribute__((address_space(3)))

__device__ __forceinline__ void gload16(const void* g, void* l) {
  __builtin_amdgcn_global_load_lds((const AS1G void*)g, (AS3L void*)l, 16, 0, 0);
}

// ---------------- x fp32 -> bf16 ----------------
__global__ __launch_bounds__(256) void k_xconv(const float* __restrict__ x, __bf16* __restrict__ xb) {
  size_t i = ((size_t)blockIdx.x * 256 + threadIdx.x) * 8;
  const float4* p = (const float4*)(x + i);
  float4 a = p[0], b = p[1];
  bf16x8 v;
  v[0] = (__bf16)a.x; v[1] = (__bf16)a.y; v[2] = (__bf16)a.z; v[3] = (__bf16)a.w;
  v[4] = (__bf16)b.x; v[5] = (__bf16)b.y; v[6] = (__bf16)b.z; v[7] = (__bf16)b.w;
  *(bf16x8*)(xb + i) = v;
}

// ---------------- W [d][e] fp32 -> Wt [z][e][d] bf16 ----------------
__global__ __launch_bounds__(256) void k_wt(const float* __restrict__ Wq, const float* __restrict__ Wk,
                                            const float* __restrict__ Wv, __bf16* __restrict__ Wt) {
  __shared__ float t[32][33];
  int z = blockIdx.z;
  const float* W = (z == 0) ? Wq : (z == 1 ? Wk : Wv);
  int r0 = blockIdx.y * 32, c0 = blockIdx.x * 32;
  int tr = threadIdx.x >> 5, tc = threadIdx.x & 31;
#pragma unroll
  for (int p = 0; p < 4; p++)
    t[tr + p * 8][tc] = W[(size_t)(r0 + tr + p * 8) * 512 + c0 + tc];
  __syncthreads();
#pragma unroll
  for (int p = 0; p < 4; p++)
    Wt[(size_t)z * 262144 + (size_t)(c0 + tr + p * 8) * 512 + r0 + tc] = (__bf16)t[tc][tr + p * 8];
}

// ---------------- fused QKV GEMM: C = xb * Wz^T + bias ----------------
// 128x128 tile, BK=64, 4 waves (2x2 of 64x64), 16x16x32 bf16 MFMA,
// global_load_lds staging with XOR-8 chunk swizzle (pre-swizzled source).
__global__ __launch_bounds__(256) void k_gemm(const __bf16* __restrict__ xb, const __bf16* __restrict__ Wt,
                                              const float* __restrict__ bq, const float* __restrict__ bk,
                                              const float* __restrict__ bv,
                                              __bf16* __restrict__ Qb, __bf16* __restrict__ Kb,
                                              __bf16* __restrict__ Vb) {
  __shared__ __bf16 sA[128 * 64];
  __shared__ __bf16 sB[128 * 64];
  int z = blockIdx.y;
  int bx = blockIdx.x;
  int m0 = (bx >> 2) * 128, e0 = (bx & 3) * 128;
  int tid = threadIdx.x, w = tid >> 6, l = tid & 63;
  int lr = l & 15, lg = l >> 4;
  int wm = (w & 1) * 64, wn = (w >> 1) * 64;
  const float* bias = (z == 0) ? bq : (z == 1 ? bk : bv);
  __bf16* dst = (z == 0) ? Qb : (z == 1 ? Kb : Vb);
  const __bf16* Wz = Wt + (size_t)z * 262144;

  float bval[4];
#pragma unroll
  for (int fn = 0; fn < 4; fn++) bval[fn] = bias[e0 + wn + fn * 16 + lr];

  f32x4 zero4 = {0.f, 0.f, 0.f, 0.f};
  f32x4 acc[4][4];
#pragma unroll
  for (int fm = 0; fm < 4; fm++)
#pragma unroll
    for (int fn = 0; fn < 4; fn++) acc[fm][fn] = zero4;

#pragma unroll 1
  for (int kt = 0; kt < 8; kt++) {
#pragma unroll
    for (int ii = 0; ii < 4; ii++) {
      int rt = (w * 4 + ii) * 8 + (l >> 3);
      int sw = ((l & 7) ^ (l >> 3)) << 3;  // source chunk pre-swizzle (elements)
      gload16(xb + (size_t)(m0 + rt) * 512 + kt * 64 + sw, sA + (w * 4 + ii) * 512);
      gload16(Wz + (size_t)(e0 + rt) * 512 + kt * 64 + sw, sB + (w * 4 + ii) * 512);
    }
    __syncthreads();
#pragma unroll
    for (int kc = 0; kc < 2; kc++) {
      bf16x8 af[4], bfr[4];
#pragma unroll
      for (int f = 0; f < 4; f++) {
        int ra = wm + f * 16 + lr;
        af[f] = *(const bf16x8*)(sA + ra * 64 + (((kc * 4 + lg) ^ (ra & 7)) << 3));
        int rb = wn + f * 16 + lr;
        bfr[f] = *(const bf16x8*)(sB + rb * 64 + (((kc * 4 + lg) ^ (rb & 7)) << 3));
      }
#pragma unroll
      for (int fm = 0; fm < 4; fm++)
#pragma unroll
        for (int fn = 0; fn < 4; fn++)
          acc[fm][fn] = __builtin_amdgcn_mfma_f32_16x16x32_bf16(af[fm], bfr[fn], acc[fm][fn], 0, 0, 0);
    }
    __syncthreads();
  }

  // Q is pre-scaled by log2(e)/sqrt(512) so softmax runs in exp2 domain.
  const float qmul = (z == 0) ? (1.4426950408889634f * 0.044194173824159216f) : 1.0f;
#pragma unroll
  for (int fm = 0; fm < 4; fm++)
#pragma unroll
    for (int fn = 0; fn < 4; fn++)
#pragma unroll
      for (int r = 0; r < 4; r++) {
        float v = (acc[fm][fn][r] + bval[fn]) * qmul;
        dst[(size_t)(m0 + wm + fm * 16 + lg * 4 + r) * 512 + e0 + wn + fn * 16 + lr] = (__bf16)v;
      }
}

// ---------------- Vb [b][n][e] -> Vt [b][e][n] ----------------
__global__ __launch_bounds__(256) void k_vt(const __bf16* __restrict__ Vb, __bf16* __restrict__ Vt) {
  __shared__ unsigned short t[64][65];
  int b = blockIdx.z;
  int n0 = blockIdx.x * 64, e0 = blockIdx.y * 64;
  const unsigned short* V = (const unsigned short*)Vb + (size_t)b * 2048 * 512;
  unsigned short* T = (unsigned short*)Vt + (size_t)b * 512 * 2048;
  int tn = threadIdx.x >> 5, te = (threadIdx.x & 31) * 2;
#pragma unroll
  for (int p = 0; p < 8; p++) {
    int r = tn + p * 8;
    ushort2 v = *(const ushort2*)&V[(size_t)(n0 + r) * 512 + e0 + te];
    t[r][te] = v.x;
    t[r][te + 1] = v.y;
  }
  __syncthreads();
#pragma unroll
  for (int p = 0; p < 8; p++) {
    int e = tn + p * 8;
    ushort2 o2;
    o2.x = t[te][e];
    o2.y = t[te + 1][e];
    *(ushort2*)&T[(size_t)(e0 + e) * 2048 + n0 + te] = o2;
  }
}

// ---------------- flash attention ----------------
// grid 256: batch = blockIdx&7 (pins batch to one XCD's L2), qtile = blockIdx>>3.
// 4 waves x 16 q-rows = 64 q-rows/block; KV tile 64; K[64][512] + Vt-slice[512][64]
// staged via global_load_lds with XOR-8 chunk swizzle; P bounced via LDS (stride 144B).
__global__ __launch_bounds__(256, 1) void k_fa(const __bf16* __restrict__ Qb, const __bf16* __restrict__ Kb,
                                               const __bf16* __restrict__ Vt, float* __restrict__ out) {
  extern __shared__ char smem[];
  __bf16* sK = (__bf16*)smem;             // [64][512] chunk-swizzled, 64KB
  __bf16* sV = (__bf16*)(smem + 65536);   // [512][64] chunk-swizzled, 64KB
  int tid = threadIdx.x;
  int w = tid >> 6, l = tid & 63;
  int lr = l & 15, lg = l >> 4;
  __bf16* sP = (__bf16*)(smem + 131072) + w * 1152;  // per-wave [16][72] bf16

  int b = blockIdx.x & 7;
  int qt = blockIdx.x >> 3;
  int q0 = qt * 64;

  // Q A-fragments, held in registers for the whole kernel (already scaled).
  bf16x8 qf[16];
  const __bf16* qrow = Qb + (size_t)(b * 2048 + q0 + w * 16 + lr) * 512;
#pragma unroll
  for (int dk = 0; dk < 16; dk++) qf[dk] = *(const bf16x8*)(qrow + dk * 32 + lg * 8);

  f32x4 zero4 = {0.f, 0.f, 0.f, 0.f};
  f32x4 o[32];
#pragma unroll
  for (int dj = 0; dj < 32; dj++) o[dj] = zero4;
  float m_run[4] = {-1e30f, -1e30f, -1e30f, -1e30f};
  float l_run[4] = {0.f, 0.f, 0.f, 0.f};

  const __bf16* Kbase = Kb + (size_t)b * 2048 * 512;
  const __bf16* Vbase = Vt + (size_t)b * 512 * 2048;

#pragma unroll 1
  for (int kv0 = 0; kv0 < 2048; kv0 += 64) {
    // stage K tile [64][512]: one 1KB row per instr, 16 per wave
#pragma unroll
    for (int i = 0; i < 16; i++) {
      int row = w * 16 + i;
      gload16(Kbase + (size_t)(kv0 + row) * 512 + ((l ^ (i & 7)) << 3), sK + row * 512);
    }
    // stage V^T slice [512][64]: 8 rows (128B each) per instr, 16 per wave
#pragma unroll
    for (int i = 0; i < 16; i++) {
      int row = w * 128 + i * 8 + (l >> 3);
      gload16(Vbase + (size_t)row * 2048 + kv0 + (((l & 7) ^ (l >> 3)) << 3),
              sV + (w * 128 + i * 8) * 64);
    }
    __syncthreads();

    // S = Q K^T (exp2 domain, scale folded into Q)
    f32x4 s[4];
#pragma unroll
    for (int j = 0; j < 4; j++) s[j] = zero4;
#pragma unroll
    for (int dk = 0; dk < 16; dk++) {
#pragma unroll
      for (int j = 0; j < 4; j++) {
        int row = j * 16 + lr;
        bf16x8 kf = *(const bf16x8*)(sK + row * 512 + (((dk * 4 + lg) ^ (row & 7)) << 3));
        s[j] = __builtin_amdgcn_mfma_f32_16x16x32_bf16(qf[dk], kf, s[j], 0, 0, 0);
      }
    }

    // online softmax: row = lg*4 + r, cols across 16 lanes (lr) x 4 frags
#pragma unroll
    for (int r = 0; r < 4; r++) {
      float mt = fmaxf(fmaxf(s[0][r], s[1][r]), fmaxf(s[2][r], s[3][r]));
#pragma unroll
      for (int msk = 1; msk <= 8; msk <<= 1) mt = fmaxf(mt, __shfl_xor(mt, msk));
      float mnew = fmaxf(m_run[r], mt);
      float al = exp2f(m_run[r] - mnew);
      float pv0 = exp2f(s[0][r] - mnew);
      float pv1 = exp2f(s[1][r] - mnew);
      float pv2 = exp2f(s[2][r] - mnew);
      float pv3 = exp2f(s[3][r] - mnew);
      float ps = pv0 + pv1 + pv2 + pv3;
#pragma unroll
      for (int msk = 1; msk <= 8; msk <<= 1) ps += __shfl_xor(ps, msk);
      l_run[r] = l_run[r] * al + ps;
      m_run[r] = mnew;
      sP[(lg * 4 + r) * 72 + lr] = (__bf16)pv0;
      sP[(lg * 4 + r) * 72 + 16 + lr] = (__bf16)pv1;
      sP[(lg * 4 + r) * 72 + 32 + lr] = (__bf16)pv2;
      sP[(lg * 4 + r) * 72 + 48 + lr] = (__bf16)pv3;
#pragma unroll
      for (int dj = 0; dj < 32; dj++) o[dj][r] *= al;
    }

    // P as A-fragments (wave-private LDS bounce; in-order LDS within wave)
    bf16x8 pa0 = *(const bf16x8*)(sP + lr * 72 + lg * 8);
    bf16x8 pa1 = *(const bf16x8*)(sP + lr * 72 + 32 + lg * 8);

    // O += P * V
#pragma unroll
    for (int dj = 0; dj < 32; dj++) {
      int row = dj * 16 + lr;
      bf16x8 v0 = *(const bf16x8*)(sV + row * 64 + ((lg ^ (row & 7)) << 3));
      bf16x8 v1 = *(const bf16x8*)(sV + row * 64 + (((4 + lg) ^ (row & 7)) << 3));
      o[dj] = __builtin_amdgcn_mfma_f32_16x16x32_bf16(pa0, v0, o[dj], 0, 0, 0);
      o[dj] = __builtin_amdgcn_mfma_f32_16x16x32_bf16(pa1, v1, o[dj], 0, 0, 0);
    }
    __syncthreads();
  }

  float inv[4];
#pragma unroll
  for (int r = 0; r < 4; r++) inv[r] = 1.0f / l_run[r];
  float* orow = out + (size_t)(b * 2048 + q0 + w * 16 + lg * 4) * 512;
#pragma unroll
  for (int dj = 0; dj < 32; dj++)
#pragma unroll
    for (int r = 0; r < 4; r++)
      orow[(size_t)r * 512 + dj * 16 + lr] = o[dj][r] * inv[r];
}

extern "C" void kernel_launch(void* const* d_in, const int* in_sizes, int n_in,
                              void* d_out, int out_size, void* d_ws, size_t ws_size,
                              hipStream_t stream) {
  (void)in_sizes; (void)n_in; (void)out_size; (void)ws_size;
  const float* x = (const float*)d_in[0];
  const float* Wq = (const float*)d_in[1];
  const float* bq = (const float*)d_in[2];
  const float* Wk = (const float*)d_in[3];
  const float* bk = (const float*)d_in[4];
  const float* Wv = (const float*)d_in[5];
  const float* bv = (const float*)d_in[6];
  float* out = (float*)d_out;
  char* ws = (char*)d_ws;
  __bf16* xb = (__bf16*)(ws);
  __bf16* Qb = (__bf16*)(ws + 16777216);
  __bf16* Kb = (__bf16*)(ws + 33554432);
  __bf16* Vb = (__bf16*)(ws + 50331648);
  __bf16* Vt = (__bf16*)(ws + 67108864);
  __bf16* Wt = (__bf16*)(ws + 83886080);

  hipFuncSetAttribute((const void*)k_fa, hipFuncAttributeMaxDynamicSharedMemorySize, 140288);

  k_xconv<<<4096, 256, 0, stream>>>(x, xb);
  k_wt<<<dim3(16, 16, 3), 256, 0, stream>>>(Wq, Wk, Wv, Wt);
  k_gemm<<<dim3(512, 3), 256, 0, stream>>>(xb, Wt, bq, bk, bv, Qb, Kb, Vb);
  k_vt<<<dim3(32, 8, 8), 256, 0, stream>>>(Vb, Vt);
  k_fa<<<256, 256, 140288, stream>>>(Qb, Kb, Vt, out);
}